// Round 4
// baseline (306.764 us; speedup 1.0000x reference)
//
#include <hip/hip_runtime.h>

typedef __attribute__((ext_vector_type(8))) short bf16x8;
typedef __attribute__((ext_vector_type(4))) float f32x4;

#define NB 1024
#define NC 64
#define NT 512
#define ND 32

__device__ __forceinline__ unsigned short f2bf(float f) {
  unsigned u = __float_as_uint(f);
  u += 0x7FFFu + ((u >> 16) & 1u);   // round-to-nearest-even (finite values)
  return (unsigned short)(u >> 16);
}

// ---- prep: rearrange weights into MFMA B-fragment order (bf16) ----
// ws layout (ushort elements):
//   [0,16384)      Win  frags [ks(16)][nt(2)][lane(64)][j(8)]   B[k][n], k=32ks+8(l>>4)+j, n=16nt+(l&15)
//   [16384,32768)  Wout frags [nt(32)][lane(64)][j(8)]
//   [32768,33792)  Wq   frags [nt(2)][lane(64)][j(8)]
//   [33792,34816)  Wk   frags
//   [34816,35840)  Wv   frags
__global__ void prep_weights(const float* __restrict__ Win, const float* __restrict__ Wq,
                             const float* __restrict__ Wk, const float* __restrict__ Wv,
                             const float* __restrict__ Wout, unsigned short* __restrict__ ws) {
  int idx = blockIdx.x * 256 + threadIdx.x;
  if (idx >= 35840) return;
  float v;
  if (idx < 16384) {
    int j = idx & 7, lane = (idx >> 3) & 63, nt = (idx >> 9) & 1, ks = idx >> 10;
    int t = 32 * ks + 8 * (lane >> 4) + j;
    int d = 16 * nt + (lane & 15);
    v = Win[t * ND + d];
  } else if (idx < 32768) {
    int p = idx - 16384;
    int j = p & 7, lane = (p >> 3) & 63, nt = (p >> 9) & 31;
    int k = 8 * (lane >> 4) + j;
    int n = 16 * nt + (lane & 15);
    v = Wout[k * NT + n];
  } else {
    int p = idx - 32768;
    const float* W = (p < 1024) ? Wq : ((p < 2048) ? Wk : Wv);
    int q = p & 1023;
    int j = q & 7, lane = (q >> 3) & 63, nt = (q >> 9) & 1;
    int t = 8 * (lane >> 4) + j;
    int d = 16 * nt + (lane & 15);
    v = W[t * ND + d];
  }
  ws[idx] = f2bf(v);
}

// ---- fused main kernel: one block per batch, 256 threads (4 waves) ----
// Register budget target: <=128 VGPR+AGPR combined -> 4 waves/SIMD -> 4 blocks/CU.
// P4 uses stream-and-recompute: pass 1 computes LN statistics with only 16 acc
// floats live; pass 2 recomputes the identical MFMAs and stores normalized y.
// LDS = 4096 (h/o frags) + 27648 (q/k/v, overlaid by LN scratch in P4) = 31744 B.
__global__ __launch_bounds__(256, 4)
void mha_main(const float* __restrict__ x, const float* __restrict__ b_in,
              const float* __restrict__ b_out, const float* __restrict__ gamma,
              const float* __restrict__ beta, const unsigned short* __restrict__ wsb,
              float* __restrict__ out) {
  __shared__ __align__(16) unsigned short lds_ho[4][64][8];  // h frags, then o frags
  __shared__ __align__(16) float lds_q[64][36];
  __shared__ __align__(16) float lds_k[64][36];
  __shared__ __align__(16) float lds_v[64][36];

  const int tid = threadIdx.x;
  const int w  = tid >> 6;   // wave id
  const int l  = tid & 63;   // lane
  const int g  = l >> 4;     // quarter-wave group
  const int lo = l & 15;
  const int b  = blockIdx.x;
  const float* __restrict__ xb = x + (size_t)b * (NC * NT);

  // ---------------- P1: h = x @ W_in + b_in  (A-frags loaded from global) -------
  const int srow = 16 * w + lo;
  const float* __restrict__ xr = xb + srow * NT + 8 * g;
  const bf16x8* __restrict__ wsWin = (const bf16x8*)wsb;

  f32x4 zero4 = (f32x4){0.f, 0.f, 0.f, 0.f};
  f32x4 acc1[2];
  acc1[0] = zero4;
  acc1[1] = zero4;
  f32x4 ra = *(const f32x4*)(xr);
  f32x4 rb = *(const f32x4*)(xr + 4);
  bf16x8 bp0 = wsWin[l];
  bf16x8 bp1 = wsWin[64 + l];

#pragma unroll
  for (int ks = 0; ks < 16; ++ks) {
    bf16x8 af;
    af[0] = (short)f2bf(ra[0]); af[1] = (short)f2bf(ra[1]);
    af[2] = (short)f2bf(ra[2]); af[3] = (short)f2bf(ra[3]);
    af[4] = (short)f2bf(rb[0]); af[5] = (short)f2bf(rb[1]);
    af[6] = (short)f2bf(rb[2]); af[7] = (short)f2bf(rb[3]);
    int nk = (ks < 15) ? (ks + 1) : 15;   // prefetch next chunk (clamped)
    f32x4 ra2 = *(const f32x4*)(xr + 32 * nk);
    f32x4 rb2 = *(const f32x4*)(xr + 32 * nk + 4);
    bf16x8 bn0 = wsWin[(2 * nk) * 64 + l];
    bf16x8 bn1 = wsWin[(2 * nk + 1) * 64 + l];
    acc1[0] = __builtin_amdgcn_mfma_f32_16x16x32_bf16(af, bp0, acc1[0], 0, 0, 0);
    acc1[1] = __builtin_amdgcn_mfma_f32_16x16x32_bf16(af, bp1, acc1[1], 0, 0, 0);
    ra = ra2; rb = rb2; bp0 = bn0; bp1 = bn1;
  }

  float binv0 = b_in[lo];
  float binv1 = b_in[16 + lo];
  // D-frag: row = 16w + 4g + r, col = 16nt + lo  -> h into frag-direct LDS (bf16)
#pragma unroll
  for (int nt = 0; nt < 2; ++nt) {
#pragma unroll
    for (int r = 0; r < 4; ++r) {
      float hv = acc1[nt][r] + (nt ? binv1 : binv0);
      int cc = 2 * nt + (lo >> 3);
      int slotlane = (4 * g + r) | (cc << 4);
      lds_ho[w][slotlane][lo & 7] = f2bf(hv);
    }
  }
  __syncthreads();

  // ---------------- P2: q/k/v = h @ Wq/Wk/Wv  (6 MFMAs per wave) ----------------
  const bf16x8* __restrict__ wsWq = (const bf16x8*)(wsb + 32768);
  const bf16x8* __restrict__ wsWk = (const bf16x8*)(wsb + 33792);
  const bf16x8* __restrict__ wsWv = (const bf16x8*)(wsb + 34816);
  bf16x8 ah = *(const bf16x8*)&lds_ho[w][l][0];
  f32x4 qacc[2], kacc[2], vacc[2];
#pragma unroll
  for (int nt = 0; nt < 2; ++nt) {
    qacc[nt] = __builtin_amdgcn_mfma_f32_16x16x32_bf16(ah, wsWq[nt * 64 + l], zero4, 0, 0, 0);
    kacc[nt] = __builtin_amdgcn_mfma_f32_16x16x32_bf16(ah, wsWk[nt * 64 + l], zero4, 0, 0, 0);
    vacc[nt] = __builtin_amdgcn_mfma_f32_16x16x32_bf16(ah, wsWv[nt * 64 + l], zero4, 0, 0, 0);
  }
#pragma unroll
  for (int nt = 0; nt < 2; ++nt) {
#pragma unroll
    for (int r = 0; r < 4; ++r) {
      int row = 16 * w + 4 * g + r;
      int col = 16 * nt + lo;
      lds_q[row][col] = qacc[nt][r];
      lds_k[row][col] = kacc[nt][r];
      lds_v[row][col] = vacc[nt][r];
    }
  }
  __syncthreads();

  // ---------------- P3: attention, thread = (channel c = lane, head = wave) -----
  {
    const int c = l, hd = w;
    const f32x4 qv0 = *(const f32x4*)&lds_q[c][8 * hd];
    const f32x4 qv1 = *(const f32x4*)&lds_q[c][8 * hd + 4];
    float sc[64];
    float mx = -3.4e38f;
#pragma unroll
    for (int kk = 0; kk < 64; ++kk) {
      f32x4 k0 = *(const f32x4*)&lds_k[kk][8 * hd];
      f32x4 k1 = *(const f32x4*)&lds_k[kk][8 * hd + 4];
      float s = qv0[0] * k0[0] + qv0[1] * k0[1] + qv0[2] * k0[2] + qv0[3] * k0[3]
              + qv1[0] * k1[0] + qv1[1] * k1[1] + qv1[2] * k1[2] + qv1[3] * k1[3];
      s *= 0.35355339059327373f;  // 1/sqrt(8)
      sc[kk] = s;
      mx = fmaxf(mx, s);
    }
    float sum = 0.f;
#pragma unroll
    for (int kk = 0; kk < 64; ++kk) {
      float p = exp2f((sc[kk] - mx) * 1.4426950408889634f);
      sc[kk] = p;
      sum += p;
    }
    float inv = 1.0f / sum;
    float ov[8] = {0.f, 0.f, 0.f, 0.f, 0.f, 0.f, 0.f, 0.f};
#pragma unroll
    for (int kk = 0; kk < 64; ++kk) {
      f32x4 v0 = *(const f32x4*)&lds_v[kk][8 * hd];
      f32x4 v1 = *(const f32x4*)&lds_v[kk][8 * hd + 4];
      float p = sc[kk];
      ov[0] += p * v0[0]; ov[1] += p * v0[1]; ov[2] += p * v0[2]; ov[3] += p * v0[3];
      ov[4] += p * v1[0]; ov[5] += p * v1[1]; ov[6] += p * v1[2]; ov[7] += p * v1[3];
    }
    bf16x8 opk;
#pragma unroll
    for (int d = 0; d < 8; ++d) opk[d] = (short)f2bf(ov[d] * inv);
    // o[c][8hd+d] -> frag slot [c>>4][(c&15)|(hd<<4)][d]  (h is dead; reuse lds_ho)
    *(bf16x8*)&lds_ho[c >> 4][(c & 15) | (hd << 4)][0] = opk;
  }
  __syncthreads();

  // ---------------- P4: y = o @ W_out + b_out + x, LayerNorm (2-pass) -----------
  // LN scratch overlays dead q/k/v region
  float* red0 = &lds_q[0][0];           // [4][64]
  float* red1 = red0 + 256;             // [4][64]
  float* mu_a = red0 + 512;             // [64]
  float* rs_a = red0 + 576;             // [64]

  bf16x8 a4[4];
#pragma unroll
  for (int mt = 0; mt < 4; ++mt) a4[mt] = *(const bf16x8*)&lds_ho[mt][l][0];
  const bf16x8* __restrict__ wsWout = (const bf16x8*)(wsb + 16384);

  const int colbase = 128 * w + lo;
  float bo[8];
#pragma unroll
  for (int nt = 0; nt < 8; ++nt) bo[nt] = b_out[colbase + 16 * nt];

  float s1[4][4], s2[4][4];
#pragma unroll
  for (int mt = 0; mt < 4; ++mt)
#pragma unroll
    for (int r = 0; r < 4; ++r) { s1[mt][r] = 0.f; s2[mt][r] = 0.f; }

  // ---- pass 1: statistics only (16 acc floats live per nt step) ----
#pragma unroll
  for (int nt = 0; nt < 8; ++nt) {
    bf16x8 bfr = wsWout[(8 * w + nt) * 64 + l];
    f32x4 acc[4];
#pragma unroll
    for (int mt = 0; mt < 4; ++mt)
      acc[mt] = __builtin_amdgcn_mfma_f32_16x16x32_bf16(a4[mt], bfr, zero4, 0, 0, 0);
#pragma unroll
    for (int mt = 0; mt < 4; ++mt) {
#pragma unroll
      for (int r = 0; r < 4; ++r) {
        int row = 16 * mt + 4 * g + r;
        float y = acc[mt][r] + bo[nt] + xb[row * NT + colbase + 16 * nt];
        s1[mt][r] += y;
        s2[mt][r] += y * y;
      }
    }
  }
  // reduce across the 16 lanes (lo) sharing each row set
#pragma unroll
  for (int off = 1; off <= 8; off <<= 1) {
#pragma unroll
    for (int mt = 0; mt < 4; ++mt)
#pragma unroll
      for (int r = 0; r < 4; ++r) {
        s1[mt][r] += __shfl_xor(s1[mt][r], off, 64);
        s2[mt][r] += __shfl_xor(s2[mt][r], off, 64);
      }
  }
#pragma unroll
  for (int mt = 0; mt < 4; ++mt)
#pragma unroll
    for (int r = 0; r < 4; ++r)
      if (lo == (r * 4 + mt)) {
        int row = 16 * mt + 4 * g + r;
        red0[w * 64 + row] = s1[mt][r];
        red1[w * 64 + row] = s2[mt][r];
      }
  __syncthreads();
  if (tid < 64) {
    float s = red0[tid] + red0[64 + tid] + red0[128 + tid] + red0[192 + tid];
    float q2 = red1[tid] + red1[64 + tid] + red1[128 + tid] + red1[192 + tid];
    float mu = s * (1.0f / 512.0f);
    float var = q2 * (1.0f / 512.0f) - mu * mu;
    mu_a[tid] = mu;
    rs_a[tid] = rsqrtf(var + 1e-5f);
  }
  __syncthreads();

  // ---- pass 2: recompute identical MFMAs, normalize, store ----
  float gm[8], bt[8];
#pragma unroll
  for (int nt = 0; nt < 8; ++nt) {
    gm[nt] = gamma[colbase + 16 * nt];
    bt[nt] = beta[colbase + 16 * nt];
  }
  float* __restrict__ ob = out + (size_t)b * (NC * NT);
#pragma unroll
  for (int nt = 0; nt < 8; ++nt) {
    bf16x8 bfr = wsWout[(8 * w + nt) * 64 + l];
    f32x4 acc[4];
#pragma unroll
    for (int mt = 0; mt < 4; ++mt)
      acc[mt] = __builtin_amdgcn_mfma_f32_16x16x32_bf16(a4[mt], bfr, zero4, 0, 0, 0);
#pragma unroll
    for (int mt = 0; mt < 4; ++mt) {
#pragma unroll
      for (int r = 0; r < 4; ++r) {
        int row = 16 * mt + 4 * g + r;
        float y = acc[mt][r] + bo[nt] + xb[row * NT + colbase + 16 * nt];
        ob[row * NT + colbase + 16 * nt] = (y - mu_a[row]) * rs_a[row] * gm[nt] + bt[nt];
      }
    }
  }
}

extern "C" void kernel_launch(void* const* d_in, const int* in_sizes, int n_in,
                              void* d_out, int out_size, void* d_ws, size_t ws_size,
                              hipStream_t stream) {
  const float* x     = (const float*)d_in[0];
  const float* W_in  = (const float*)d_in[1];
  const float* b_in  = (const float*)d_in[2];
  const float* W_q   = (const float*)d_in[3];
  const float* W_k   = (const float*)d_in[4];
  const float* W_v   = (const float*)d_in[5];
  const float* W_out = (const float*)d_in[6];
  const float* b_out = (const float*)d_in[7];
  const float* gamma = (const float*)d_in[8];
  const float* beta  = (const float*)d_in[9];
  unsigned short* ws = (unsigned short*)d_ws;

  prep_weights<<<140, 256, 0, stream>>>(W_in, W_q, W_k, W_v, W_out, ws);
  mha_main<<<NB, 256, 0, stream>>>(x, b_in, b_out, gamma, beta, ws, (float*)d_out);
}

// Round 5
// 277.223 us; speedup vs baseline: 1.1066x; 1.1066x over previous
//
#include <hip/hip_runtime.h>

typedef __attribute__((ext_vector_type(8))) short bf16x8;
typedef __attribute__((ext_vector_type(4))) float f32x4;

#define NB 1024
#define NC 64
#define NT 512
#define ND 32

__device__ __forceinline__ unsigned short f2bf(float f) {
  unsigned u = __float_as_uint(f);
  u += 0x7FFFu + ((u >> 16) & 1u);   // round-to-nearest-even (finite values)
  return (unsigned short)(u >> 16);
}

// ---- prep: rearrange weights into MFMA B-fragment order (bf16) ----
// ws layout (ushort elements):
//   [0,16384)      Win  frags [ks(16)][nt(2)][lane(64)][j(8)]   B[k][n], k=32ks+8(l>>4)+j, n=16nt+(l&15)
//   [16384,32768)  Wout frags [nt(32)][lane(64)][j(8)]
//   [32768,33792)  Wq   frags [nt(2)][lane(64)][j(8)]
//   [33792,34816)  Wk   frags
//   [34816,35840)  Wv   frags
__global__ void prep_weights(const float* __restrict__ Win, const float* __restrict__ Wq,
                             const float* __restrict__ Wk, const float* __restrict__ Wv,
                             const float* __restrict__ Wout, unsigned short* __restrict__ ws) {
  int idx = blockIdx.x * 256 + threadIdx.x;
  if (idx >= 35840) return;
  float v;
  if (idx < 16384) {
    int j = idx & 7, lane = (idx >> 3) & 63, nt = (idx >> 9) & 1, ks = idx >> 10;
    int t = 32 * ks + 8 * (lane >> 4) + j;
    int d = 16 * nt + (lane & 15);
    v = Win[t * ND + d];
  } else if (idx < 32768) {
    int p = idx - 16384;
    int j = p & 7, lane = (p >> 3) & 63, nt = (p >> 9) & 31;
    int k = 8 * (lane >> 4) + j;
    int n = 16 * nt + (lane & 15);
    v = Wout[k * NT + n];
  } else {
    int p = idx - 32768;
    const float* W = (p < 1024) ? Wq : ((p < 2048) ? Wk : Wv);
    int q = p & 1023;
    int j = q & 7, lane = (q >> 3) & 63, nt = (q >> 9) & 1;
    int t = 8 * (lane >> 4) + j;
    int d = 16 * nt + (lane & 15);
    v = W[t * ND + d];
  }
  ws[idx] = f2bf(v);
}

// ---- fused main kernel: one block per batch, 256 threads (4 waves) ----
// Register budget: <=128 VGPR+AGPR -> 4 waves/SIMD -> 4 blocks/CU.
// P3 uses online no-max softmax (scores bounded ~|3|, exp2 safe in f32),
// so no sc[64] array (R4's spill cause). P4 is stream-and-recompute.
// LDS = 4096 (h/o frags) + 27648 (q/k/v, overlaid by LN scratch in P4) = 31744 B.
__global__ __launch_bounds__(256, 4)
void mha_main(const float* __restrict__ x, const float* __restrict__ b_in,
              const float* __restrict__ b_out, const float* __restrict__ gamma,
              const float* __restrict__ beta, const unsigned short* __restrict__ wsb,
              float* __restrict__ out) {
  __shared__ __align__(16) unsigned short lds_ho[4][64][8];  // h frags, then o frags
  __shared__ __align__(16) float lds_q[64][36];
  __shared__ __align__(16) float lds_k[64][36];
  __shared__ __align__(16) float lds_v[64][36];

  const int tid = threadIdx.x;
  const int w  = tid >> 6;   // wave id
  const int l  = tid & 63;   // lane
  const int g  = l >> 4;     // quarter-wave group
  const int lo = l & 15;
  const int b  = blockIdx.x;
  const float* __restrict__ xb = x + (size_t)b * (NC * NT);

  // ---------------- P1: h = x @ W_in + b_in  (A-frags loaded from global) -------
  const int srow = 16 * w + lo;
  const float* __restrict__ xr = xb + srow * NT + 8 * g;
  const bf16x8* __restrict__ wsWin = (const bf16x8*)wsb;

  f32x4 zero4 = (f32x4){0.f, 0.f, 0.f, 0.f};
  f32x4 acc1[2];
  acc1[0] = zero4;
  acc1[1] = zero4;
  f32x4 ra = *(const f32x4*)(xr);
  f32x4 rb = *(const f32x4*)(xr + 4);
  bf16x8 bp0 = wsWin[l];
  bf16x8 bp1 = wsWin[64 + l];

#pragma unroll
  for (int ks = 0; ks < 16; ++ks) {
    bf16x8 af;
    af[0] = (short)f2bf(ra[0]); af[1] = (short)f2bf(ra[1]);
    af[2] = (short)f2bf(ra[2]); af[3] = (short)f2bf(ra[3]);
    af[4] = (short)f2bf(rb[0]); af[5] = (short)f2bf(rb[1]);
    af[6] = (short)f2bf(rb[2]); af[7] = (short)f2bf(rb[3]);
    int nk = (ks < 15) ? (ks + 1) : 15;   // prefetch next chunk (clamped)
    f32x4 ra2 = *(const f32x4*)(xr + 32 * nk);
    f32x4 rb2 = *(const f32x4*)(xr + 32 * nk + 4);
    bf16x8 bn0 = wsWin[(2 * nk) * 64 + l];
    bf16x8 bn1 = wsWin[(2 * nk + 1) * 64 + l];
    acc1[0] = __builtin_amdgcn_mfma_f32_16x16x32_bf16(af, bp0, acc1[0], 0, 0, 0);
    acc1[1] = __builtin_amdgcn_mfma_f32_16x16x32_bf16(af, bp1, acc1[1], 0, 0, 0);
    ra = ra2; rb = rb2; bp0 = bn0; bp1 = bn1;
  }

  float binv0 = b_in[lo];
  float binv1 = b_in[16 + lo];
  // D-frag: row = 16w + 4g + r, col = 16nt + lo  -> h into frag-direct LDS (bf16)
#pragma unroll
  for (int nt = 0; nt < 2; ++nt) {
#pragma unroll
    for (int r = 0; r < 4; ++r) {
      float hv = acc1[nt][r] + (nt ? binv1 : binv0);
      int cc = 2 * nt + (lo >> 3);
      int slotlane = (4 * g + r) | (cc << 4);
      lds_ho[w][slotlane][lo & 7] = f2bf(hv);
    }
  }
  __syncthreads();

  // ---------------- P2: q/k/v = h @ Wq/Wk/Wv  (6 MFMAs per wave) ----------------
  const bf16x8* __restrict__ wsWq = (const bf16x8*)(wsb + 32768);
  const bf16x8* __restrict__ wsWk = (const bf16x8*)(wsb + 33792);
  const bf16x8* __restrict__ wsWv = (const bf16x8*)(wsb + 34816);
  bf16x8 ah = *(const bf16x8*)&lds_ho[w][l][0];
  f32x4 qacc[2], kacc[2], vacc[2];
#pragma unroll
  for (int nt = 0; nt < 2; ++nt) {
    qacc[nt] = __builtin_amdgcn_mfma_f32_16x16x32_bf16(ah, wsWq[nt * 64 + l], zero4, 0, 0, 0);
    kacc[nt] = __builtin_amdgcn_mfma_f32_16x16x32_bf16(ah, wsWk[nt * 64 + l], zero4, 0, 0, 0);
    vacc[nt] = __builtin_amdgcn_mfma_f32_16x16x32_bf16(ah, wsWv[nt * 64 + l], zero4, 0, 0, 0);
  }
#pragma unroll
  for (int nt = 0; nt < 2; ++nt) {
#pragma unroll
    for (int r = 0; r < 4; ++r) {
      int row = 16 * w + 4 * g + r;
      int col = 16 * nt + lo;
      lds_q[row][col] = qacc[nt][r];
      lds_k[row][col] = kacc[nt][r];
      lds_v[row][col] = vacc[nt][r];
    }
  }
  __syncthreads();

  // ---------------- P3: attention, online no-max softmax ------------------------
  // thread = (channel c = lane, head = wave); scores |s| <~ 3 so exp2 is f32-safe
  {
    const int hd = w;
    const f32x4 qv0 = *(const f32x4*)&lds_q[l][8 * hd];
    const f32x4 qv1 = *(const f32x4*)&lds_q[l][8 * hd + 4];
    float sum = 0.f;
    float ov[8] = {0.f, 0.f, 0.f, 0.f, 0.f, 0.f, 0.f, 0.f};
#pragma unroll 4
    for (int kk = 0; kk < 64; ++kk) {
      f32x4 k0 = *(const f32x4*)&lds_k[kk][8 * hd];
      f32x4 k1 = *(const f32x4*)&lds_k[kk][8 * hd + 4];
      float s = qv0[0] * k0[0] + qv0[1] * k0[1] + qv0[2] * k0[2] + qv0[3] * k0[3]
              + qv1[0] * k1[0] + qv1[1] * k1[1] + qv1[2] * k1[2] + qv1[3] * k1[3];
      float p = exp2f(s * (1.4426950408889634f * 0.35355339059327373f));
      sum += p;
      f32x4 v0 = *(const f32x4*)&lds_v[kk][8 * hd];
      f32x4 v1 = *(const f32x4*)&lds_v[kk][8 * hd + 4];
      ov[0] += p * v0[0]; ov[1] += p * v0[1]; ov[2] += p * v0[2]; ov[3] += p * v0[3];
      ov[4] += p * v1[0]; ov[5] += p * v1[1]; ov[6] += p * v1[2]; ov[7] += p * v1[3];
    }
    float inv = 1.0f / sum;
    bf16x8 opk;
#pragma unroll
    for (int d = 0; d < 8; ++d) opk[d] = (short)f2bf(ov[d] * inv);
    // o[c][8hd+d] -> frag slot [c>>4][(c&15)|(hd<<4)][d]  (h is dead; reuse lds_ho)
    *(bf16x8*)&lds_ho[l >> 4][(l & 15) | (hd << 4)][0] = opk;
  }
  __syncthreads();

  // ---------------- P4: y = o @ W_out + b_out + x, LayerNorm (2-pass) -----------
  // LN scratch overlays dead q/k/v region
  float* red0 = &lds_q[0][0];           // [4][64]
  float* red1 = red0 + 256;             // [4][64]
  float* mu_a = red0 + 512;             // [64]
  float* rs_a = red0 + 576;             // [64]

  bf16x8 a4[4];
#pragma unroll
  for (int mt = 0; mt < 4; ++mt) a4[mt] = *(const bf16x8*)&lds_ho[mt][l][0];
  const bf16x8* __restrict__ wsWout = (const bf16x8*)(wsb + 16384);

  const int colbase = 128 * w + lo;
  float bo[8];
#pragma unroll
  for (int nt = 0; nt < 8; ++nt) bo[nt] = b_out[colbase + 16 * nt];

  float s1[4][4], s2[4][4];
#pragma unroll
  for (int mt = 0; mt < 4; ++mt)
#pragma unroll
    for (int r = 0; r < 4; ++r) { s1[mt][r] = 0.f; s2[mt][r] = 0.f; }

  // ---- pass 1: statistics only (16 acc floats live per nt step) ----
#pragma unroll
  for (int nt = 0; nt < 8; ++nt) {
    bf16x8 bfr = wsWout[(8 * w + nt) * 64 + l];
    f32x4 acc[4];
#pragma unroll
    for (int mt = 0; mt < 4; ++mt)
      acc[mt] = __builtin_amdgcn_mfma_f32_16x16x32_bf16(a4[mt], bfr, zero4, 0, 0, 0);
#pragma unroll
    for (int mt = 0; mt < 4; ++mt) {
#pragma unroll
      for (int r = 0; r < 4; ++r) {
        int row = 16 * mt + 4 * g + r;
        float y = acc[mt][r] + bo[nt] + xb[row * NT + colbase + 16 * nt];
        s1[mt][r] += y;
        s2[mt][r] += y * y;
      }
    }
  }
  // reduce across the 16 lanes (lo) sharing each row set
#pragma unroll
  for (int off = 1; off <= 8; off <<= 1) {
#pragma unroll
    for (int mt = 0; mt < 4; ++mt)
#pragma unroll
      for (int r = 0; r < 4; ++r) {
        s1[mt][r] += __shfl_xor(s1[mt][r], off, 64);
        s2[mt][r] += __shfl_xor(s2[mt][r], off, 64);
      }
  }
#pragma unroll
  for (int mt = 0; mt < 4; ++mt)
#pragma unroll
    for (int r = 0; r < 4; ++r)
      if (lo == (r * 4 + mt)) {
        int row = 16 * mt + 4 * g + r;
        red0[w * 64 + row] = s1[mt][r];
        red1[w * 64 + row] = s2[mt][r];
      }
  __syncthreads();
  if (tid < 64) {
    float s = red0[tid] + red0[64 + tid] + red0[128 + tid] + red0[192 + tid];
    float q2 = red1[tid] + red1[64 + tid] + red1[128 + tid] + red1[192 + tid];
    float mu = s * (1.0f / 512.0f);
    float var = q2 * (1.0f / 512.0f) - mu * mu;
    mu_a[tid] = mu;
    rs_a[tid] = rsqrtf(var + 1e-5f);
  }
  __syncthreads();

  // ---- pass 2: recompute identical MFMAs, normalize, store ----
  float gm[8], bt[8];
#pragma unroll
  for (int nt = 0; nt < 8; ++nt) {
    gm[nt] = gamma[colbase + 16 * nt];
    bt[nt] = beta[colbase + 16 * nt];
  }
  float* __restrict__ ob = out + (size_t)b * (NC * NT);
#pragma unroll
  for (int nt = 0; nt < 8; ++nt) {
    bf16x8 bfr = wsWout[(8 * w + nt) * 64 + l];
    f32x4 acc[4];
#pragma unroll
    for (int mt = 0; mt < 4; ++mt)
      acc[mt] = __builtin_amdgcn_mfma_f32_16x16x32_bf16(a4[mt], bfr, zero4, 0, 0, 0);
#pragma unroll
    for (int mt = 0; mt < 4; ++mt) {
#pragma unroll
      for (int r = 0; r < 4; ++r) {
        int row = 16 * mt + 4 * g + r;
        float y = acc[mt][r] + bo[nt] + xb[row * NT + colbase + 16 * nt];
        ob[row * NT + colbase + 16 * nt] = (y - mu_a[row]) * rs_a[row] * gm[nt] + bt[nt];
      }
    }
  }
}

extern "C" void kernel_launch(void* const* d_in, const int* in_sizes, int n_in,
                              void* d_out, int out_size, void* d_ws, size_t ws_size,
                              hipStream_t stream) {
  const float* x     = (const float*)d_in[0];
  const float* W_in  = (const float*)d_in[1];
  const float* b_in  = (const float*)d_in[2];
  const float* W_q   = (const float*)d_in[3];
  const float* W_k   = (const float*)d_in[4];
  const float* W_v   = (const float*)d_in[5];
  const float* W_out = (const float*)d_in[6];
  const float* b_out = (const float*)d_in[7];
  const float* gamma = (const float*)d_in[8];
  const float* beta  = (const float*)d_in[9];
  unsigned short* ws = (unsigned short*)d_ws;

  prep_weights<<<140, 256, 0, stream>>>(W_in, W_q, W_k, W_v, W_out, ws);
  mha_main<<<NB, 256, 0, stream>>>(x, b_in, b_out, gamma, beta, ws, (float*)d_out);
}

// Round 6
// 86.532 us; speedup vs baseline: 3.5451x; 3.2037x over previous
//
#include <hip/hip_runtime.h>

typedef __attribute__((ext_vector_type(8))) short bf16x8;
typedef __attribute__((ext_vector_type(4))) float f32x4;

#define NB 1024
#define NC 64
#define NT 512
#define ND 32

__device__ __forceinline__ unsigned short f2bf(float f) {
  unsigned u = __float_as_uint(f);
  u += 0x7FFFu + ((u >> 16) & 1u);   // round-to-nearest-even (finite values)
  return (unsigned short)(u >> 16);
}

// ---- prep: rearrange weights into MFMA B-fragment order (bf16) ----
// ws layout (ushort elements):
//   [0,16384)      Win  frags [ks(16)][nt(2)][lane(64)][j(8)]   B[k][n], k=32ks+8(l>>4)+j, n=16nt+(l&15)
//   [16384,32768)  Wout frags [nt(32)][lane(64)][j(8)]
//   [32768,33792)  Wq   frags [nt(2)][lane(64)][j(8)]
//   [33792,34816)  Wk   frags
//   [34816,35840)  Wv   frags
__global__ void prep_weights(const float* __restrict__ Win, const float* __restrict__ Wq,
                             const float* __restrict__ Wk, const float* __restrict__ Wv,
                             const float* __restrict__ Wout, unsigned short* __restrict__ ws) {
  int idx = blockIdx.x * 256 + threadIdx.x;
  if (idx >= 35840) return;
  float v;
  if (idx < 16384) {
    int j = idx & 7, lane = (idx >> 3) & 63, nt = (idx >> 9) & 1, ks = idx >> 10;
    int t = 32 * ks + 8 * (lane >> 4) + j;
    int d = 16 * nt + (lane & 15);
    v = Win[t * ND + d];
  } else if (idx < 32768) {
    int p = idx - 16384;
    int j = p & 7, lane = (p >> 3) & 63, nt = (p >> 9) & 31;
    int k = 8 * (lane >> 4) + j;
    int n = 16 * nt + (lane & 15);
    v = Wout[k * NT + n];
  } else {
    int p = idx - 32768;
    const float* W = (p < 1024) ? Wq : ((p < 2048) ? Wk : Wv);
    int q = p & 1023;
    int j = q & 7, lane = (q >> 3) & 63, nt = (q >> 9) & 1;
    int t = 8 * (lane >> 4) + j;
    int d = 16 * nt + (lane & 15);
    v = W[t * ND + d];
  }
  ws[idx] = f2bf(v);
}

// ---- fused main kernel: one block per batch, 256 threads (4 waves) ----
// Register budget: <=128 unified (64 VGPR + 64 AGPR) -> 4 waves/SIMD.
// P3: online no-max softmax (scores |s|<~3, exp2 f32-safe) -> no score array.
// P4: wave w owns ROW TILE w (16 rows) x ALL 512 cols -> per thread only 4 rows:
//     s1/s2[4] live (8 regs), one acc, LN reduce = pure 16-lane shfl, no LDS.
//     Stream-and-recompute (pass 2 re-does identical MFMAs) keeps acc tiny.
// LDS = 4096 (h/o frags) + 27648 (q/k/v f32) = 31744 B.
__global__ __launch_bounds__(256, 4)
void mha_main(const float* __restrict__ x, const float* __restrict__ b_in,
              const float* __restrict__ b_out, const float* __restrict__ gamma,
              const float* __restrict__ beta, const unsigned short* __restrict__ wsb,
              float* __restrict__ out) {
  __shared__ __align__(16) unsigned short lds_ho[4][64][8];  // h frags, then o frags
  __shared__ __align__(16) float lds_q[64][36];
  __shared__ __align__(16) float lds_k[64][36];
  __shared__ __align__(16) float lds_v[64][36];

  const int tid = threadIdx.x;
  const int w  = tid >> 6;   // wave id
  const int l  = tid & 63;   // lane
  const int g  = l >> 4;     // quarter-wave group
  const int lo = l & 15;
  const int b  = blockIdx.x;
  const float* __restrict__ xb = x + (size_t)b * (NC * NT);

  // ---------------- P1: h = x @ W_in + b_in  (A-frags loaded from global) -------
  const int srow = 16 * w + lo;
  const float* __restrict__ xr = xb + srow * NT + 8 * g;
  const bf16x8* __restrict__ wsWin = (const bf16x8*)wsb;

  f32x4 zero4 = (f32x4){0.f, 0.f, 0.f, 0.f};
  f32x4 acc1[2];
  acc1[0] = zero4;
  acc1[1] = zero4;
  f32x4 ra = *(const f32x4*)(xr);
  f32x4 rb = *(const f32x4*)(xr + 4);
  bf16x8 bp0 = wsWin[l];
  bf16x8 bp1 = wsWin[64 + l];

#pragma unroll
  for (int ks = 0; ks < 16; ++ks) {
    bf16x8 af;
    af[0] = (short)f2bf(ra[0]); af[1] = (short)f2bf(ra[1]);
    af[2] = (short)f2bf(ra[2]); af[3] = (short)f2bf(ra[3]);
    af[4] = (short)f2bf(rb[0]); af[5] = (short)f2bf(rb[1]);
    af[6] = (short)f2bf(rb[2]); af[7] = (short)f2bf(rb[3]);
    int nk = (ks < 15) ? (ks + 1) : 15;   // prefetch next chunk (clamped)
    f32x4 ra2 = *(const f32x4*)(xr + 32 * nk);
    f32x4 rb2 = *(const f32x4*)(xr + 32 * nk + 4);
    bf16x8 bn0 = wsWin[(2 * nk) * 64 + l];
    bf16x8 bn1 = wsWin[(2 * nk + 1) * 64 + l];
    acc1[0] = __builtin_amdgcn_mfma_f32_16x16x32_bf16(af, bp0, acc1[0], 0, 0, 0);
    acc1[1] = __builtin_amdgcn_mfma_f32_16x16x32_bf16(af, bp1, acc1[1], 0, 0, 0);
    ra = ra2; rb = rb2; bp0 = bn0; bp1 = bn1;
  }

  float binv0 = b_in[lo];
  float binv1 = b_in[16 + lo];
  // D-frag: row = 16w + 4g + r, col = 16nt + lo  -> h into frag-direct LDS (bf16)
#pragma unroll
  for (int nt = 0; nt < 2; ++nt) {
#pragma unroll
    for (int r = 0; r < 4; ++r) {
      float hv = acc1[nt][r] + (nt ? binv1 : binv0);
      int cc = 2 * nt + (lo >> 3);
      int slotlane = (4 * g + r) | (cc << 4);
      lds_ho[w][slotlane][lo & 7] = f2bf(hv);
    }
  }
  __syncthreads();

  // ---------------- P2: q/k/v = h @ Wq/Wk/Wv  (6 MFMAs per wave) ----------------
  const bf16x8* __restrict__ wsWq = (const bf16x8*)(wsb + 32768);
  const bf16x8* __restrict__ wsWk = (const bf16x8*)(wsb + 33792);
  const bf16x8* __restrict__ wsWv = (const bf16x8*)(wsb + 34816);
  bf16x8 ah = *(const bf16x8*)&lds_ho[w][l][0];
  f32x4 qacc[2], kacc[2], vacc[2];
#pragma unroll
  for (int nt = 0; nt < 2; ++nt) {
    qacc[nt] = __builtin_amdgcn_mfma_f32_16x16x32_bf16(ah, wsWq[nt * 64 + l], zero4, 0, 0, 0);
    kacc[nt] = __builtin_amdgcn_mfma_f32_16x16x32_bf16(ah, wsWk[nt * 64 + l], zero4, 0, 0, 0);
    vacc[nt] = __builtin_amdgcn_mfma_f32_16x16x32_bf16(ah, wsWv[nt * 64 + l], zero4, 0, 0, 0);
  }
#pragma unroll
  for (int nt = 0; nt < 2; ++nt) {
#pragma unroll
    for (int r = 0; r < 4; ++r) {
      int row = 16 * w + 4 * g + r;
      int col = 16 * nt + lo;
      lds_q[row][col] = qacc[nt][r];
      lds_k[row][col] = kacc[nt][r];
      lds_v[row][col] = vacc[nt][r];
    }
  }
  __syncthreads();

  // ---------------- P3: attention, online no-max softmax ------------------------
  // thread = (channel c = lane, head = wave); scores |s| <~ 3 so exp2 is f32-safe
  {
    const int hd = w;
    const f32x4 qv0 = *(const f32x4*)&lds_q[l][8 * hd];
    const f32x4 qv1 = *(const f32x4*)&lds_q[l][8 * hd + 4];
    float sum = 0.f;
    float ov[8] = {0.f, 0.f, 0.f, 0.f, 0.f, 0.f, 0.f, 0.f};
#pragma unroll 4
    for (int kk = 0; kk < 64; ++kk) {
      f32x4 k0 = *(const f32x4*)&lds_k[kk][8 * hd];
      f32x4 k1 = *(const f32x4*)&lds_k[kk][8 * hd + 4];
      float s = qv0[0] * k0[0] + qv0[1] * k0[1] + qv0[2] * k0[2] + qv0[3] * k0[3]
              + qv1[0] * k1[0] + qv1[1] * k1[1] + qv1[2] * k1[2] + qv1[3] * k1[3];
      float p = exp2f(s * (1.4426950408889634f * 0.35355339059327373f));
      sum += p;
      f32x4 v0 = *(const f32x4*)&lds_v[kk][8 * hd];
      f32x4 v1 = *(const f32x4*)&lds_v[kk][8 * hd + 4];
      ov[0] += p * v0[0]; ov[1] += p * v0[1]; ov[2] += p * v0[2]; ov[3] += p * v0[3];
      ov[4] += p * v1[0]; ov[5] += p * v1[1]; ov[6] += p * v1[2]; ov[7] += p * v1[3];
    }
    float inv = 1.0f / sum;
    bf16x8 opk;
#pragma unroll
    for (int d = 0; d < 8; ++d) opk[d] = (short)f2bf(ov[d] * inv);
    // o[c][8hd+d] -> frag slot [c>>4][(c&15)|(hd<<4)][d]  (h is dead; reuse lds_ho)
    *(bf16x8*)&lds_ho[l >> 4][(l & 15) | (hd << 4)][0] = opk;
  }
  __syncthreads();

  // ---------------- P4: y = o @ W_out + b_out + x, LayerNorm --------------------
  // wave w owns rows 16w..16w+15, ALL 512 cols; thread owns 4 rows (16w+4g+r).
  const bf16x8 a4 = *(const bf16x8*)&lds_ho[w][l][0];
  const bf16x8* __restrict__ wsWout = (const bf16x8*)(wsb + 16384);
  const int row0 = 16 * w + 4 * g;
  const float* __restrict__ xrow = xb + row0 * NT + lo;

  float s1[4] = {0.f, 0.f, 0.f, 0.f};
  float s2[4] = {0.f, 0.f, 0.f, 0.f};

  // ---- pass 1: statistics only ----
#pragma unroll 4
  for (int nt = 0; nt < 32; ++nt) {
    bf16x8 bfr = wsWout[nt * 64 + l];
    f32x4 acc = __builtin_amdgcn_mfma_f32_16x16x32_bf16(a4, bfr, zero4, 0, 0, 0);
    int col = 16 * nt;
    float bo = b_out[col + lo];
#pragma unroll
    for (int r = 0; r < 4; ++r) {
      float y = acc[r] + bo + xrow[r * NT + col];
      s1[r] += y;
      s2[r] += y * y;
    }
  }
  // LN reduce: each row's 512 cols live in the 16 lanes sharing g
#pragma unroll
  for (int off = 1; off <= 8; off <<= 1) {
#pragma unroll
    for (int r = 0; r < 4; ++r) {
      s1[r] += __shfl_xor(s1[r], off, 64);
      s2[r] += __shfl_xor(s2[r], off, 64);
    }
  }
  float mu[4], rs[4];
#pragma unroll
  for (int r = 0; r < 4; ++r) {
    mu[r] = s1[r] * (1.0f / 512.0f);
    float var = s2[r] * (1.0f / 512.0f) - mu[r] * mu[r];
    rs[r] = rsqrtf(var + 1e-5f);
  }

  // ---- pass 2: recompute identical MFMAs, normalize, store ----
  float* __restrict__ orow = out + (size_t)b * (NC * NT) + row0 * NT + lo;
#pragma unroll 4
  for (int nt = 0; nt < 32; ++nt) {
    bf16x8 bfr = wsWout[nt * 64 + l];
    f32x4 acc = __builtin_amdgcn_mfma_f32_16x16x32_bf16(a4, bfr, zero4, 0, 0, 0);
    int col = 16 * nt;
    float bo = b_out[col + lo];
    float gm = gamma[col + lo];
    float bt = beta[col + lo];
#pragma unroll
    for (int r = 0; r < 4; ++r) {
      float y = acc[r] + bo + xrow[r * NT + col];
      orow[r * NT + col] = (y - mu[r]) * rs[r] * gm + bt;
    }
  }
}

extern "C" void kernel_launch(void* const* d_in, const int* in_sizes, int n_in,
                              void* d_out, int out_size, void* d_ws, size_t ws_size,
                              hipStream_t stream) {
  const float* x     = (const float*)d_in[0];
  const float* W_in  = (const float*)d_in[1];
  const float* b_in  = (const float*)d_in[2];
  const float* W_q   = (const float*)d_in[3];
  const float* W_k   = (const float*)d_in[4];
  const float* W_v   = (const float*)d_in[5];
  const float* W_out = (const float*)d_in[6];
  const float* b_out = (const float*)d_in[7];
  const float* gamma = (const float*)d_in[8];
  const float* beta  = (const float*)d_in[9];
  unsigned short* ws = (unsigned short*)d_ws;

  prep_weights<<<140, 256, 0, stream>>>(W_in, W_q, W_k, W_v, W_out, ws);
  mha_main<<<NB, 256, 0, stream>>>(x, b_in, b_out, gamma, beta, ws, (float*)d_out);
}